// Round 2
// baseline (9188.081 us; speedup 1.0000x reference)
//
#include <hip/hip_runtime.h>
#include <cstdio>

#define N_NODES 41616
#define N_EDGES 249696

// ------------------------- graph setup -------------------------

__global__ void k_deg(const int* __restrict__ dst, int* __restrict__ deg) {
  int e = blockIdx.x * 256 + threadIdx.x;
  if (e < N_EDGES) atomicAdd(&deg[dst[e]], 1);
}

__global__ void k_dinv(const int* __restrict__ deg, float* __restrict__ dinv) {
  int n = blockIdx.x * 256 + threadIdx.x;
  if (n < N_NODES) {
    int d = deg[n];
    dinv[n] = d > 0 ? rsqrtf((float)d) : 0.f;
  }
}

__global__ void k_blocksum(const int* __restrict__ deg, int* __restrict__ bsum) {
  __shared__ int s[256];
  int b = blockIdx.x, tid = threadIdx.x;
  int base = b * 1024;
  int acc = 0;
  for (int j = 0; j < 4; ++j) {
    int i = base + j * 256 + tid;
    if (i < N_NODES) acc += deg[i];
  }
  s[tid] = acc;
  __syncthreads();
  for (int off = 128; off > 0; off >>= 1) {
    if (tid < off) s[tid] += s[tid + off];
    __syncthreads();
  }
  if (tid == 0) bsum[b] = s[0];
}

__global__ void k_scan_bsum(const int* __restrict__ bsum, int* __restrict__ boff,
                            int nb, int* __restrict__ row_off) {
  if (threadIdx.x == 0 && blockIdx.x == 0) {
    int run = 0;
    for (int j = 0; j < nb; ++j) { boff[j] = run; run += bsum[j]; }
    row_off[N_NODES] = run;
  }
}

__global__ void k_scan_chunk(const int* __restrict__ deg, const int* __restrict__ boff,
                             int* __restrict__ row_off) {
  __shared__ int s[1024];
  int b = blockIdx.x, tid = threadIdx.x;
  int i = b * 1024 + tid;
  int v = (i < N_NODES) ? deg[i] : 0;
  s[tid] = v;
  __syncthreads();
  for (int off = 1; off < 1024; off <<= 1) {
    int t = (tid >= off) ? s[tid - off] : 0;
    __syncthreads();
    s[tid] += t;
    __syncthreads();
  }
  if (i < N_NODES) row_off[i] = boff[b] + s[tid] - v;  // exclusive prefix
}

__global__ void k_fill(const int* __restrict__ src, const int* __restrict__ dst,
                       const float* __restrict__ dinv, const int* __restrict__ row_off,
                       int* __restrict__ cursor, int* __restrict__ esrc,
                       float* __restrict__ ew) {
  int e = blockIdx.x * 256 + threadIdx.x;
  if (e >= N_EDGES) return;
  int d = dst[e], sn = src[e];
  int pos = atomicAdd(&cursor[d], 1);
  int o = row_off[d] + pos;
  esrc[o] = sn;
  ew[o] = -dinv[sn] * dinv[d];
}

// ------------------------- MLP front-end -------------------------

__global__ void k_mlp1(const float* __restrict__ vec, const float* __restrict__ w1,
                       const float* __restrict__ b1, float* __restrict__ v1) {
  int idx = blockIdx.x * 256 + threadIdx.x;
  if (idx >= 16 * 128) return;
  int g = idx >> 7, j = idx & 127;
  float acc = b1[j];
  for (int i = 0; i < 32; ++i) acc += vec[g * 32 + i] * w1[i * 128 + j];
  v1[idx] = fmaxf(acc, 0.f);
}

__global__ void k_mlp2(const float* __restrict__ v1, const float* __restrict__ w2,
                       const float* __restrict__ b2, float* __restrict__ x0) {
  __shared__ float sv[2048];
  int tid = threadIdx.x;
  for (int i = tid; i < 2048; i += 256) sv[i] = v1[i];
  __syncthreads();
  int r = blockIdx.x * 256 + tid;
  if (r >= 15606) return;
  float bb = b2[r];
  float acc[16];
#pragma unroll
  for (int g = 0; g < 16; ++g) acc[g] = bb;
  for (int i = 0; i < 128; ++i) {
    float wv = w2[i * 15606 + r];
#pragma unroll
    for (int g = 0; g < 16; ++g) acc[g] += sv[g * 128 + i] * wv;
  }
  int q = r / 6, cc = r - q * 6;
#pragma unroll
  for (int g = 0; g < 16; ++g) {
    int node = g * 2601 + q;
    x0[node * 9 + 3 + cc] = fmaxf(acc[g], 0.f);
  }
}

__global__ void k_pos(const float* __restrict__ sp, float* __restrict__ x0) {
  int idx = blockIdx.x * 256 + threadIdx.x;
  if (idx >= N_NODES * 3) return;
  int n = idx / 3, c = idx - n * 3;
  x0[n * 9 + c] = sp[idx];
}

// ------------------------- propagation (L_hat apply) -------------------------
// out = alpha * segment_sum(w * x[src]) + beta * prev   (out==prev is safe:
// each thread reads prev[idx] then writes out[idx], same location)

template <int CC>
__global__ void k_prop(const float* __restrict__ x, const float* __restrict__ prev,
                       float* __restrict__ out, const int* __restrict__ row_off,
                       const int* __restrict__ esrc, const float* __restrict__ ew,
                       float alpha, float beta) {
  int idx = blockIdx.x * 256 + threadIdx.x;
  if (idx >= N_NODES * CC) return;
  int n = idx / CC, c = idx - n * CC;
  int e0 = row_off[n], e1 = row_off[n + 1];
  float acc = 0.f;
  for (int e = e0; e < e1; ++e) acc += ew[e] * x[esrc[e] * CC + c];
  float o = alpha * acc;
  if (beta != 0.f) o += beta * prev[idx];
  out[idx] = o;
}

// ------------------------- GEMMs -------------------------
// flags: 1=init (else accumulate into OUT), 2=+bias, 4=relu, 8=+res

__global__ __launch_bounds__(256) void k_gemm128(
    const float* __restrict__ A, const float* __restrict__ W, float* __restrict__ OUT,
    const float* __restrict__ bias, const float* __restrict__ res, int flags) {
  __shared__ float As[32][132];
  int row0 = blockIdx.x * 32;
  int tid = threadIdx.x;
#pragma unroll
  for (int i = 0; i < 16; ++i) {
    int idx = tid + i * 256;
    int r = idx >> 7, cc = idx & 127;
    int gr = row0 + r;
    As[r][cc] = (gr < N_NODES) ? A[gr * 128 + cc] : 0.f;
  }
  __syncthreads();
  int tc = (tid & 31) * 4;
  int tr = (tid >> 5) * 4;
  float acc[4][4] = {};
#pragma unroll 4
  for (int k = 0; k < 128; ++k) {
    float4 w4 = *reinterpret_cast<const float4*>(W + k * 128 + tc);
    float a0 = As[tr + 0][k], a1 = As[tr + 1][k], a2 = As[tr + 2][k], a3 = As[tr + 3][k];
    acc[0][0] += a0 * w4.x; acc[0][1] += a0 * w4.y; acc[0][2] += a0 * w4.z; acc[0][3] += a0 * w4.w;
    acc[1][0] += a1 * w4.x; acc[1][1] += a1 * w4.y; acc[1][2] += a1 * w4.z; acc[1][3] += a1 * w4.w;
    acc[2][0] += a2 * w4.x; acc[2][1] += a2 * w4.y; acc[2][2] += a2 * w4.z; acc[2][3] += a2 * w4.w;
    acc[3][0] += a3 * w4.x; acc[3][1] += a3 * w4.y; acc[3][2] += a3 * w4.z; acc[3][3] += a3 * w4.w;
  }
#pragma unroll
  for (int i = 0; i < 4; ++i) {
    int gr = row0 + tr + i;
    if (gr >= N_NODES) continue;
    float v0 = acc[i][0], v1 = acc[i][1], v2 = acc[i][2], v3 = acc[i][3];
    float* dp = OUT + gr * 128 + tc;
    if (!(flags & 1)) {
      float4 o = *reinterpret_cast<const float4*>(dp);
      v0 += o.x; v1 += o.y; v2 += o.z; v3 += o.w;
    }
    if (flags & 2) { v0 += bias[tc]; v1 += bias[tc + 1]; v2 += bias[tc + 2]; v3 += bias[tc + 3]; }
    if (flags & 4) { v0 = fmaxf(v0, 0.f); v1 = fmaxf(v1, 0.f); v2 = fmaxf(v2, 0.f); v3 = fmaxf(v3, 0.f); }
    if (flags & 8) {
      float4 r4 = *reinterpret_cast<const float4*>(res + gr * 128 + tc);
      v0 += r4.x; v1 += r4.y; v2 += r4.z; v3 += r4.w;
    }
    float4 o4 = {v0, v1, v2, v3};
    *reinterpret_cast<float4*>(dp) = o4;
  }
}

__global__ void k_gemm9(const float* __restrict__ A, const float* __restrict__ W,
                        float* __restrict__ OUT, const float* __restrict__ bias, int flags) {
  int idx = blockIdx.x * 256 + threadIdx.x;
  if (idx >= N_NODES * 128) return;
  int n = idx >> 7, c = idx & 127;
  float acc = (flags & 1) ? 0.f : OUT[idx];
#pragma unroll
  for (int i = 0; i < 9; ++i) acc += A[n * 9 + i] * W[i * 128 + c];
  if (flags & 2) acc += bias[c];
  OUT[idx] = acc;
}

__global__ __launch_bounds__(256) void k_gemv3(
    const float* __restrict__ A, const float* __restrict__ W, float* __restrict__ OUT,
    const float* __restrict__ bias, int flags) {
  __shared__ float As[64][129];
  int node0 = blockIdx.x * 64;
  int tid = threadIdx.x;
#pragma unroll
  for (int i = 0; i < 32; ++i) {
    int idx = tid + i * 256;
    int r = idx >> 7, cc = idx & 127;
    int gn = node0 + r;
    As[r][cc] = (gn < N_NODES) ? A[gn * 128 + cc] : 0.f;
  }
  __syncthreads();
  if (tid >= 192) return;
  int ln = tid / 3, c = tid - ln * 3;
  int gn = node0 + ln;
  if (gn >= N_NODES) return;
  float acc = (flags & 1) ? 0.f : OUT[gn * 3 + c];
  for (int k = 0; k < 128; ++k) acc += As[ln][k] * W[k * 3 + c];
  if (flags & 2) acc = tanhf(acc + bias[c]);
  OUT[gn * 3 + c] = acc;
}

// ------------------------- host -------------------------

extern "C" void kernel_launch(void* const* d_in, const int* in_sizes, int n_in,
                              void* d_out, int out_size, void* d_ws, size_t ws_size,
                              hipStream_t stream) {
  const float* vec = (const float*)d_in[0];
  const int* edges = (const int*)d_in[1];
  const float* sp  = (const float*)d_in[2];
  const float* w1  = (const float*)d_in[3];
  const float* b1  = (const float*)d_in[4];
  const float* w2  = (const float*)d_in[5];
  const float* b2  = (const float*)d_in[6];
  const float* Wi  = (const float*)d_in[7];
  const float* bi  = (const float*)d_in[8];
  const float* Wb  = (const float*)d_in[9];
  const float* bbp = (const float*)d_in[10];
  const float* Wf  = (const float*)d_in[11];
  const float* bf  = (const float*)d_in[12];
  float* out = (float*)d_out;

  const int* src = edges;
  const int* dst = edges + N_EDGES;

  size_t off = 0;
  auto alloc = [&](size_t bytes) -> void* {
    size_t o = (off + 255) & ~(size_t)255;
    off = o + bytes;
    return (void*)((char*)d_ws + o);
  };
  int* deg      = (int*)alloc((size_t)N_NODES * 4);
  float* dinv   = (float*)alloc((size_t)N_NODES * 4);
  int* row_off  = (int*)alloc((size_t)(N_NODES + 1) * 4);
  int* cursor   = (int*)alloc((size_t)N_NODES * 4);
  int* bsum     = (int*)alloc(64 * 4);
  int* boff     = (int*)alloc(64 * 4);
  int* esrc     = (int*)alloc((size_t)N_EDGES * 4);
  float* ew     = (float*)alloc((size_t)N_EDGES * 4);
  float* v1     = (float*)alloc(2048 * 4);
  float* x0     = (float*)alloc((size_t)N_NODES * 9 * 4);
  float* t19    = (float*)alloc((size_t)N_NODES * 9 * 4);
  float* t29    = (float*)alloc((size_t)N_NODES * 9 * 4);
  float* P[5];
  for (int i = 0; i < 5; ++i) P[i] = (float*)alloc((size_t)N_NODES * 128 * 4);
  if (off > ws_size) {
    fprintf(stderr, "kernel_launch: ws too small (need %zu, have %zu)\n", off, ws_size);
    return;
  }

  const int NCH = (N_NODES + 1023) / 1024;  // 41 scan chunks
  hipMemsetAsync(deg, 0, (size_t)N_NODES * 4, stream);
  hipMemsetAsync(cursor, 0, (size_t)N_NODES * 4, stream);
  k_deg<<<(N_EDGES + 255) / 256, 256, 0, stream>>>(dst, deg);
  k_dinv<<<(N_NODES + 255) / 256, 256, 0, stream>>>(deg, dinv);
  k_blocksum<<<NCH, 256, 0, stream>>>(deg, bsum);
  k_scan_bsum<<<1, 64, 0, stream>>>(bsum, boff, NCH, row_off);
  k_scan_chunk<<<NCH, 1024, 0, stream>>>(deg, boff, row_off);
  k_fill<<<(N_EDGES + 255) / 256, 256, 0, stream>>>(src, dst, dinv, row_off, cursor, esrc, ew);

  k_mlp1<<<8, 256, 0, stream>>>(vec, w1, b1, v1);
  k_mlp2<<<(15606 + 255) / 256, 256, 0, stream>>>(v1, w2, b2, x0);
  k_pos<<<(N_NODES * 3 + 255) / 256, 256, 0, stream>>>(sp, x0);

  const int gP128 = (N_NODES * 128 + 255) / 256;
  const int gP9   = (N_NODES * 9 + 255) / 256;
  const int gG    = (N_NODES + 31) / 32;
  const int gV3   = (N_NODES + 63) / 64;

  // ---- cheb_in: x0 [N,9] -> P0 [N,128] ----
  k_gemm9<<<gP128, 256, 0, stream>>>(x0, Wi + 0 * 1152, P[0], bi, 1);
  k_prop<9><<<gP9, 256, 0, stream>>>(x0, x0, t19, row_off, esrc, ew, 1.f, 0.f);
  k_gemm9<<<gP128, 256, 0, stream>>>(t19, Wi + 1 * 1152, P[0], bi, 0);
  k_prop<9><<<gP9, 256, 0, stream>>>(t19, x0, t29, row_off, esrc, ew, 2.f, -1.f);
  k_gemm9<<<gP128, 256, 0, stream>>>(t29, Wi + 2 * 1152, P[0], bi, 0);
  k_prop<9><<<gP9, 256, 0, stream>>>(t29, t19, t19, row_off, esrc, ew, 2.f, -1.f);
  k_gemm9<<<gP128, 256, 0, stream>>>(t19, Wi + 3 * 1152, P[0], bi, 0);
  k_prop<9><<<gP9, 256, 0, stream>>>(t19, t29, t29, row_off, esrc, ew, 2.f, -1.f);
  k_gemm9<<<gP128, 256, 0, stream>>>(t29, Wi + 4 * 1152, P[0], bi, 0);
  k_prop<9><<<gP9, 256, 0, stream>>>(t29, t19, t19, row_off, esrc, ew, 2.f, -1.f);
  k_gemm9<<<gP128, 256, 0, stream>>>(t19, Wi + 5 * 1152, P[0], bi, 2);

  // ---- 6 residual blocks x 3 chebs (128->128) ----
  auto cheb128 = [&](const float* in, const float* Wk, const float* bk, float* OUTb,
                     float* wa, float* wb, const float* resb, int lastflags) {
    k_gemm128<<<gG, 256, 0, stream>>>(in, Wk + 0 * 16384, OUTb, bk, resb, 1);
    k_prop<128><<<gP128, 256, 0, stream>>>(in, in, wa, row_off, esrc, ew, 1.f, 0.f);
    k_gemm128<<<gG, 256, 0, stream>>>(wa, Wk + 1 * 16384, OUTb, bk, resb, 0);
    k_prop<128><<<gP128, 256, 0, stream>>>(wa, in, wb, row_off, esrc, ew, 2.f, -1.f);
    k_gemm128<<<gG, 256, 0, stream>>>(wb, Wk + 2 * 16384, OUTb, bk, resb, 0);
    k_prop<128><<<gP128, 256, 0, stream>>>(wb, wa, wa, row_off, esrc, ew, 2.f, -1.f);
    k_gemm128<<<gG, 256, 0, stream>>>(wa, Wk + 3 * 16384, OUTb, bk, resb, 0);
    k_prop<128><<<gP128, 256, 0, stream>>>(wa, wb, wb, row_off, esrc, ew, 2.f, -1.f);
    k_gemm128<<<gG, 256, 0, stream>>>(wb, Wk + 4 * 16384, OUTb, bk, resb, 0);
    k_prop<128><<<gP128, 256, 0, stream>>>(wb, wa, wa, row_off, esrc, ew, 2.f, -1.f);
    k_gemm128<<<gG, 256, 0, stream>>>(wa, Wk + 5 * 16384, OUTb, bk, resb, lastflags);
  };

  float* cur = P[0];
  float* s1 = P[3];
  float* s2 = P[4];
  for (int blk = 0; blk < 6; ++blk) {
    const float* resb = cur;
    const float* W0 = Wb + (size_t)(3 * blk + 0) * 6 * 16384;
    const float* W1 = Wb + (size_t)(3 * blk + 1) * 6 * 16384;
    const float* W2 = Wb + (size_t)(3 * blk + 2) * 6 * 16384;
    cheb128(cur, W0, bbp + (3 * blk + 0) * 128, s1, P[1], P[2], nullptr, 2 | 4);
    cheb128(s1, W1, bbp + (3 * blk + 1) * 128, s2, P[1], P[2], nullptr, 2 | 4);
    cheb128(s2, W2, bbp + (3 * blk + 2) * 128, s1, P[1], P[2], resb, 2 | 4 | 8);
    float* tmp = cur; cur = s1; s1 = tmp;
  }

  // ---- final cheb: cur [N,128] -> out [N,3], tanh ----
  k_gemv3<<<gV3, 256, 0, stream>>>(cur, Wf + 0 * 384, out, bf, 1);
  k_prop<128><<<gP128, 256, 0, stream>>>(cur, cur, P[1], row_off, esrc, ew, 1.f, 0.f);
  k_gemv3<<<gV3, 256, 0, stream>>>(P[1], Wf + 1 * 384, out, bf, 0);
  k_prop<128><<<gP128, 256, 0, stream>>>(P[1], cur, P[2], row_off, esrc, ew, 2.f, -1.f);
  k_gemv3<<<gV3, 256, 0, stream>>>(P[2], Wf + 2 * 384, out, bf, 0);
  k_prop<128><<<gP128, 256, 0, stream>>>(P[2], P[1], P[1], row_off, esrc, ew, 2.f, -1.f);
  k_gemv3<<<gV3, 256, 0, stream>>>(P[1], Wf + 3 * 384, out, bf, 0);
  k_prop<128><<<gP128, 256, 0, stream>>>(P[1], P[2], P[2], row_off, esrc, ew, 2.f, -1.f);
  k_gemv3<<<gV3, 256, 0, stream>>>(P[2], Wf + 4 * 384, out, bf, 0);
  k_prop<128><<<gP128, 256, 0, stream>>>(P[2], P[1], P[1], row_off, esrc, ew, 2.f, -1.f);
  k_gemv3<<<gV3, 256, 0, stream>>>(P[1], Wf + 5 * 384, out, bf, 2);
}

// Round 3
// 5268.406 us; speedup vs baseline: 1.7440x; 1.7440x over previous
//
#include <hip/hip_runtime.h>
#include <cstdio>

#define N_NODES 41616
#define N_EDGES 249696

// ------------------------- graph setup -------------------------

__global__ void k_deg(const int* __restrict__ dst, int* __restrict__ deg) {
  int e = blockIdx.x * 256 + threadIdx.x;
  if (e < N_EDGES) atomicAdd(&deg[dst[e]], 1);
}

__global__ void k_dinv(const int* __restrict__ deg, float* __restrict__ dinv) {
  int n = blockIdx.x * 256 + threadIdx.x;
  if (n < N_NODES) {
    int d = deg[n];
    dinv[n] = d > 0 ? rsqrtf((float)d) : 0.f;
  }
}

__global__ void k_blocksum(const int* __restrict__ deg, int* __restrict__ bsum) {
  __shared__ int s[256];
  int b = blockIdx.x, tid = threadIdx.x;
  int base = b * 1024;
  int acc = 0;
  for (int j = 0; j < 4; ++j) {
    int i = base + j * 256 + tid;
    if (i < N_NODES) acc += deg[i];
  }
  s[tid] = acc;
  __syncthreads();
  for (int off = 128; off > 0; off >>= 1) {
    if (tid < off) s[tid] += s[tid + off];
    __syncthreads();
  }
  if (tid == 0) bsum[b] = s[0];
}

__global__ void k_scan_bsum(const int* __restrict__ bsum, int* __restrict__ boff,
                            int nb, int* __restrict__ row_off) {
  if (threadIdx.x == 0 && blockIdx.x == 0) {
    int run = 0;
    for (int j = 0; j < nb; ++j) { boff[j] = run; run += bsum[j]; }
    row_off[N_NODES] = run;
  }
}

__global__ void k_scan_chunk(const int* __restrict__ deg, const int* __restrict__ boff,
                             int* __restrict__ row_off) {
  __shared__ int s[1024];
  int b = blockIdx.x, tid = threadIdx.x;
  int i = b * 1024 + tid;
  int v = (i < N_NODES) ? deg[i] : 0;
  s[tid] = v;
  __syncthreads();
  for (int off = 1; off < 1024; off <<= 1) {
    int t = (tid >= off) ? s[tid - off] : 0;
    __syncthreads();
    s[tid] += t;
    __syncthreads();
  }
  if (i < N_NODES) row_off[i] = boff[b] + s[tid] - v;  // exclusive prefix
}

__global__ void k_fill(const int* __restrict__ src, const int* __restrict__ dst,
                       const float* __restrict__ dinv, const int* __restrict__ row_off,
                       int* __restrict__ cursor, int* __restrict__ esrc,
                       float* __restrict__ ew) {
  int e = blockIdx.x * 256 + threadIdx.x;
  if (e >= N_EDGES) return;
  int d = dst[e], sn = src[e];
  int pos = atomicAdd(&cursor[d], 1);
  int o = row_off[d] + pos;
  esrc[o] = sn;
  ew[o] = -dinv[sn] * dinv[d];
}

// ------------------------- MLP front-end -------------------------

__global__ void k_mlp1(const float* __restrict__ vec, const float* __restrict__ w1,
                       const float* __restrict__ b1, float* __restrict__ v1) {
  int idx = blockIdx.x * 256 + threadIdx.x;
  if (idx >= 16 * 128) return;
  int g = idx >> 7, j = idx & 127;
  float acc = b1[j];
  for (int i = 0; i < 32; ++i) acc += vec[g * 32 + i] * w1[i * 128 + j];
  v1[idx] = fmaxf(acc, 0.f);
}

__global__ void k_mlp2(const float* __restrict__ v1, const float* __restrict__ w2,
                       const float* __restrict__ b2, float* __restrict__ x0) {
  __shared__ float sv[2048];
  int tid = threadIdx.x;
  for (int i = tid; i < 2048; i += 256) sv[i] = v1[i];
  __syncthreads();
  int r = blockIdx.x * 256 + tid;
  if (r >= 15606) return;
  float bb = b2[r];
  float acc[16];
#pragma unroll
  for (int g = 0; g < 16; ++g) acc[g] = bb;
  for (int i = 0; i < 128; ++i) {
    float wv = w2[i * 15606 + r];
#pragma unroll
    for (int g = 0; g < 16; ++g) acc[g] += sv[g * 128 + i] * wv;
  }
  int q = r / 6, cc = r - q * 6;
#pragma unroll
  for (int g = 0; g < 16; ++g) {
    int node = g * 2601 + q;
    x0[node * 9 + 3 + cc] = fmaxf(acc[g], 0.f);
  }
}

__global__ void k_pos(const float* __restrict__ sp, float* __restrict__ x0) {
  int idx = blockIdx.x * 256 + threadIdx.x;
  if (idx >= N_NODES * 3) return;
  int n = idx / 3, c = idx - n * 3;
  x0[n * 9 + c] = sp[idx];
}

// ------------------------- propagation -------------------------
// out = alpha * segment_sum(w * x[src]) + beta * prev  (out==prev safe)

template <int CC>
__global__ void k_prop(const float* __restrict__ x, const float* __restrict__ prev,
                       float* __restrict__ out, const int* __restrict__ row_off,
                       const int* __restrict__ esrc, const float* __restrict__ ew,
                       float alpha, float beta) {
  int idx = blockIdx.x * 256 + threadIdx.x;
  if (idx >= N_NODES * CC) return;
  int n = idx / CC, c = idx - n * CC;
  int e0 = row_off[n], e1 = row_off[n + 1];
  float acc = 0.f;
  for (int e = e0; e < e1; ++e) acc += ew[e] * x[esrc[e] * CC + c];
  float o = alpha * acc;
  if (beta != 0.f) o += beta * prev[idx];
  out[idx] = o;
}

// C=128 vectorized: 32 lanes per node, float4 per lane.
__global__ __launch_bounds__(256) void k_prop128v(
    const float* __restrict__ x, const float* __restrict__ prev, float* __restrict__ out,
    const int* __restrict__ row_off, const int* __restrict__ esrc,
    const float* __restrict__ ew, float alpha, float beta) {
  int tid = threadIdx.x;
  int lane = tid & 31;
  int n = blockIdx.x * 8 + (tid >> 5);
  if (n >= N_NODES) return;
  int e0 = row_off[n], e1 = row_off[n + 1];
  const float4* xv = (const float4*)x;
  float4 acc = {0.f, 0.f, 0.f, 0.f};
  for (int e = e0; e < e1; ++e) {
    float w = ew[e];
    float4 v = xv[(size_t)esrc[e] * 32 + lane];
    acc.x += w * v.x; acc.y += w * v.y; acc.z += w * v.z; acc.w += w * v.w;
  }
  size_t oidx = (size_t)n * 32 + lane;
  float4 o = {alpha * acc.x, alpha * acc.y, alpha * acc.z, alpha * acc.w};
  if (beta != 0.f) {
    float4 p = ((const float4*)prev)[oidx];
    o.x += beta * p.x; o.y += beta * p.y; o.z += beta * p.z; o.w += beta * p.w;
  }
  ((float4*)out)[oidx] = o;
}

// ------------------------- GEMMs -------------------------
// flags: 1=init (else accumulate into OUT), 2=+bias, 4=relu, 8=+res

// OUT[64x128 tile] (+)= Ta@W3[0] + Tb@W3[1] + Tc@W3[2]
__global__ __launch_bounds__(256) void k_gemm3x(
    const float* __restrict__ Ta, const float* __restrict__ Tb, const float* __restrict__ Tc,
    const float* __restrict__ W3, float* __restrict__ OUT,
    const float* __restrict__ bias, const float* __restrict__ res, int flags) {
  __shared__ float As[64][132];
  int row0 = blockIdx.x * 64;
  int tid = threadIdx.x;
  int tc = (tid & 31) * 4;
  int tr = (tid >> 5) * 8;
  float acc[8][4] = {};
#pragma unroll
  for (int t = 0; t < 3; ++t) {
    const float* A = (t == 0) ? Ta : (t == 1) ? Tb : Tc;
    __syncthreads();
#pragma unroll
    for (int i = 0; i < 8; ++i) {
      int idx = tid + i * 256;        // float4 units over 64x32
      int r = idx >> 5, cq = idx & 31;
      int gr = row0 + r;
      float4 v = {0.f, 0.f, 0.f, 0.f};
      if (gr < N_NODES) v = ((const float4*)A)[(size_t)gr * 32 + cq];
      *(float4*)&As[r][cq * 4] = v;
    }
    __syncthreads();
    const float* W = W3 + t * 16384;
    for (int k = 0; k < 128; ++k) {
      float4 w4 = *(const float4*)(W + k * 128 + tc);
#pragma unroll
      for (int i = 0; i < 8; ++i) {
        float a = As[tr + i][k];
        acc[i][0] += a * w4.x; acc[i][1] += a * w4.y;
        acc[i][2] += a * w4.z; acc[i][3] += a * w4.w;
      }
    }
  }
#pragma unroll
  for (int i = 0; i < 8; ++i) {
    int gr = row0 + tr + i;
    if (gr >= N_NODES) continue;
    float v0 = acc[i][0], v1 = acc[i][1], v2 = acc[i][2], v3 = acc[i][3];
    float* dp = OUT + (size_t)gr * 128 + tc;
    if (!(flags & 1)) {
      float4 o = *(const float4*)dp;
      v0 += o.x; v1 += o.y; v2 += o.z; v3 += o.w;
    }
    if (flags & 2) { v0 += bias[tc]; v1 += bias[tc + 1]; v2 += bias[tc + 2]; v3 += bias[tc + 3]; }
    if (flags & 4) { v0 = fmaxf(v0, 0.f); v1 = fmaxf(v1, 0.f); v2 = fmaxf(v2, 0.f); v3 = fmaxf(v3, 0.f); }
    if (flags & 8) {
      float4 r4 = *(const float4*)(res + (size_t)gr * 128 + tc);
      v0 += r4.x; v1 += r4.y; v2 += r4.z; v3 += r4.w;
    }
    float4 o4 = {v0, v1, v2, v3};
    *(float4*)dp = o4;
  }
}

// fused input cheb: OUT[n][c] = bi[c] + sum_{q=0..53} Tq/9[n*9+q%9] * Wi[q*128+c]
__global__ __launch_bounds__(256) void k_gemm9f(
    const float* __restrict__ T0, const float* __restrict__ T1, const float* __restrict__ T2,
    const float* __restrict__ T3, const float* __restrict__ T4, const float* __restrict__ T5,
    const float* __restrict__ Wi, const float* __restrict__ bi, float* __restrict__ OUT) {
  __shared__ float sA[2][54];
  __shared__ const float* sT[6];
  int tid = threadIdx.x;
  int n0 = blockIdx.x * 2;
  if (tid == 0) { sT[0] = T0; sT[1] = T1; sT[2] = T2; sT[3] = T3; sT[4] = T4; sT[5] = T5; }
  __syncthreads();
  if (tid < 108) {
    int nl = tid / 54, q = tid % 54;
    int n = n0 + nl;
    sA[nl][q] = (n < N_NODES) ? sT[q / 9][(size_t)n * 9 + (q % 9)] : 0.f;
  }
  __syncthreads();
  int nl = tid >> 7, c = tid & 127;
  int n = n0 + nl;
  if (n >= N_NODES) return;
  float acc = bi[c];
#pragma unroll
  for (int q = 0; q < 54; ++q) acc += sA[nl][q] * Wi[q * 128 + c];
  OUT[(size_t)n * 128 + c] = acc;
}

__global__ __launch_bounds__(256) void k_gemv3(
    const float* __restrict__ A, const float* __restrict__ W, float* __restrict__ OUT,
    const float* __restrict__ bias, int flags) {
  __shared__ float As[64][129];
  int node0 = blockIdx.x * 64;
  int tid = threadIdx.x;
#pragma unroll
  for (int i = 0; i < 32; ++i) {
    int idx = tid + i * 256;
    int r = idx >> 7, cc = idx & 127;
    int gn = node0 + r;
    As[r][cc] = (gn < N_NODES) ? A[(size_t)gn * 128 + cc] : 0.f;
  }
  __syncthreads();
  if (tid >= 192) return;
  int ln = tid / 3, c = tid - ln * 3;
  int gn = node0 + ln;
  if (gn >= N_NODES) return;
  float acc = (flags & 1) ? 0.f : OUT[(size_t)gn * 3 + c];
  for (int k = 0; k < 128; ++k) acc += As[ln][k] * W[k * 3 + c];
  if (flags & 2) acc = tanhf(acc + bias[c]);
  OUT[(size_t)gn * 3 + c] = acc;
}

// ------------------------- host -------------------------

extern "C" void kernel_launch(void* const* d_in, const int* in_sizes, int n_in,
                              void* d_out, int out_size, void* d_ws, size_t ws_size,
                              hipStream_t stream) {
  const float* vec = (const float*)d_in[0];
  const int* edges = (const int*)d_in[1];
  const float* sp  = (const float*)d_in[2];
  const float* w1  = (const float*)d_in[3];
  const float* b1  = (const float*)d_in[4];
  const float* w2  = (const float*)d_in[5];
  const float* b2  = (const float*)d_in[6];
  const float* Wi  = (const float*)d_in[7];
  const float* bi  = (const float*)d_in[8];
  const float* Wb  = (const float*)d_in[9];
  const float* bbp = (const float*)d_in[10];
  const float* Wf  = (const float*)d_in[11];
  const float* bf  = (const float*)d_in[12];
  float* out = (float*)d_out;

  const int* src = edges;
  const int* dst = edges + N_EDGES;

  size_t off = 0;
  auto alloc = [&](size_t bytes) -> void* {
    size_t o = (off + 255) & ~(size_t)255;
    off = o + bytes;
    return (void*)((char*)d_ws + o);
  };
  int* deg      = (int*)alloc((size_t)N_NODES * 4);
  float* dinv   = (float*)alloc((size_t)N_NODES * 4);
  int* row_off  = (int*)alloc((size_t)(N_NODES + 1) * 4);
  int* cursor   = (int*)alloc((size_t)N_NODES * 4);
  int* bsum     = (int*)alloc(64 * 4);
  int* boff     = (int*)alloc(64 * 4);
  int* esrc     = (int*)alloc((size_t)N_EDGES * 4);
  float* ew     = (float*)alloc((size_t)N_EDGES * 4);
  float* v1     = (float*)alloc(2048 * 4);
  float* x0     = (float*)alloc((size_t)N_NODES * 9 * 4);
  float* t9[5];
  for (int i = 0; i < 5; ++i) t9[i] = (float*)alloc((size_t)N_NODES * 9 * 4);
  float* B[6];  // X, S1, S2, PA, PB, PC
  for (int i = 0; i < 6; ++i) B[i] = (float*)alloc((size_t)N_NODES * 128 * 4);
  if (off > ws_size) {
    fprintf(stderr, "kernel_launch: ws too small (need %zu, have %zu)\n", off, ws_size);
    return;
  }
  float* PA = B[3];
  float* PB = B[4];
  float* PC = B[5];

  const int NCH = (N_NODES + 1023) / 1024;
  hipMemsetAsync(deg, 0, (size_t)N_NODES * 4, stream);
  hipMemsetAsync(cursor, 0, (size_t)N_NODES * 4, stream);
  k_deg<<<(N_EDGES + 255) / 256, 256, 0, stream>>>(dst, deg);
  k_dinv<<<(N_NODES + 255) / 256, 256, 0, stream>>>(deg, dinv);
  k_blocksum<<<NCH, 256, 0, stream>>>(deg, bsum);
  k_scan_bsum<<<1, 64, 0, stream>>>(bsum, boff, NCH, row_off);
  k_scan_chunk<<<NCH, 1024, 0, stream>>>(deg, boff, row_off);
  k_fill<<<(N_EDGES + 255) / 256, 256, 0, stream>>>(src, dst, dinv, row_off, cursor, esrc, ew);

  k_mlp1<<<8, 256, 0, stream>>>(vec, w1, b1, v1);
  k_mlp2<<<(15606 + 255) / 256, 256, 0, stream>>>(v1, w2, b2, x0);
  k_pos<<<(N_NODES * 3 + 255) / 256, 256, 0, stream>>>(sp, x0);

  const int gP9  = (N_NODES * 9 + 255) / 256;
  const int gPn  = (N_NODES + 7) / 8;      // prop128v: 8 nodes/block
  const int gG64 = (N_NODES + 63) / 64;    // gemm3x / gemv3
  const int g2   = (N_NODES + 1) / 2;      // gemm9f: 2 nodes/block

  // ---- cheb_in: x0 [N,9] -> B[0] [N,128] ----
  k_prop<9><<<gP9, 256, 0, stream>>>(x0, x0, t9[0], row_off, esrc, ew, 1.f, 0.f);
  k_prop<9><<<gP9, 256, 0, stream>>>(t9[0], x0, t9[1], row_off, esrc, ew, 2.f, -1.f);
  k_prop<9><<<gP9, 256, 0, stream>>>(t9[1], t9[0], t9[2], row_off, esrc, ew, 2.f, -1.f);
  k_prop<9><<<gP9, 256, 0, stream>>>(t9[2], t9[1], t9[3], row_off, esrc, ew, 2.f, -1.f);
  k_prop<9><<<gP9, 256, 0, stream>>>(t9[3], t9[2], t9[4], row_off, esrc, ew, 2.f, -1.f);
  k_gemm9f<<<g2, 256, 0, stream>>>(x0, t9[0], t9[1], t9[2], t9[3], t9[4], Wi, bi, B[0]);

  // ---- 6 residual blocks x 3 chebs (128->128) ----
  auto cheb128 = [&](const float* in, const float* Wk, const float* bk, float* OUTb,
                     const float* resb, int lastflags) {
    k_prop128v<<<gPn, 256, 0, stream>>>(in, in, PA, row_off, esrc, ew, 1.f, 0.f);
    k_prop128v<<<gPn, 256, 0, stream>>>(PA, in, PB, row_off, esrc, ew, 2.f, -1.f);
    k_gemm3x<<<gG64, 256, 0, stream>>>(in, PA, PB, Wk, OUTb, bk, nullptr, 1 | 2);
    k_prop128v<<<gPn, 256, 0, stream>>>(PB, PA, PC, row_off, esrc, ew, 2.f, -1.f);
    k_prop128v<<<gPn, 256, 0, stream>>>(PC, PB, PA, row_off, esrc, ew, 2.f, -1.f);
    k_prop128v<<<gPn, 256, 0, stream>>>(PA, PC, PB, row_off, esrc, ew, 2.f, -1.f);
    k_gemm3x<<<gG64, 256, 0, stream>>>(PC, PA, PB, Wk + 3 * 16384, OUTb, bk, resb, lastflags);
  };

  float* cur = B[0];
  float* s1 = B[1];
  float* s2 = B[2];
  for (int blk = 0; blk < 6; ++blk) {
    const float* resb = cur;
    const float* W0 = Wb + (size_t)(3 * blk + 0) * 6 * 16384;
    const float* W1 = Wb + (size_t)(3 * blk + 1) * 6 * 16384;
    const float* W2 = Wb + (size_t)(3 * blk + 2) * 6 * 16384;
    cheb128(cur, W0, bbp + (3 * blk + 0) * 128, s1, nullptr, 4);
    cheb128(s1, W1, bbp + (3 * blk + 1) * 128, s2, nullptr, 4);
    cheb128(s2, W2, bbp + (3 * blk + 2) * 128, s1, resb, 4 | 8);
    float* tmp = cur; cur = s1; s1 = tmp;
  }

  // ---- final cheb: cur [N,128] -> out [N,3], tanh ----
  k_gemv3<<<gG64, 256, 0, stream>>>(cur, Wf + 0 * 384, out, bf, 1);
  k_prop128v<<<gPn, 256, 0, stream>>>(cur, cur, PA, row_off, esrc, ew, 1.f, 0.f);
  k_gemv3<<<gG64, 256, 0, stream>>>(PA, Wf + 1 * 384, out, bf, 0);
  k_prop128v<<<gPn, 256, 0, stream>>>(PA, cur, PB, row_off, esrc, ew, 2.f, -1.f);
  k_gemv3<<<gG64, 256, 0, stream>>>(PB, Wf + 2 * 384, out, bf, 0);
  k_prop128v<<<gPn, 256, 0, stream>>>(PB, PA, PA, row_off, esrc, ew, 2.f, -1.f);
  k_gemv3<<<gG64, 256, 0, stream>>>(PA, Wf + 3 * 384, out, bf, 0);
  k_prop128v<<<gPn, 256, 0, stream>>>(PA, PB, PB, row_off, esrc, ew, 2.f, -1.f);
  k_gemv3<<<gG64, 256, 0, stream>>>(PB, Wf + 4 * 384, out, bf, 0);
  k_prop128v<<<gPn, 256, 0, stream>>>(PB, PA, PA, row_off, esrc, ew, 2.f, -1.f);
  k_gemv3<<<gG64, 256, 0, stream>>>(PA, Wf + 5 * 384, out, bf, 2);
}